// Round 9
// baseline (196.024 us; speedup 1.0000x reference)
//
#include <hip/hip_runtime.h>
#include <hip/hip_bf16.h>
#include <stdint.h>

// B=16, M=4096, D=64, K=1024. fp32 in / fp32 out.
// Output: [z_q_st (N*D) | indices (N) | loss (1)], fp32.
//
// R20 post-mortem: busy-sum matches full issue (VALU 68k cyc/SIMD = measured
// 20%), so ~66% of cycles = all waves stalled on vmcnt. Diagnosis: L1
// line-fill (MSHR) throughput. 16 desync waves/CU x 256KB codebook stream
// through 32KB L1 = 4MB fill/CU at ~13B/cyc ~= 125us — matches 143us and the
// R15-R20 invariance (every variant moved the same fill volume).
// R21: (1) 2 rowtiles/wave (32 rows) -> halves per-CU fill to 2MB (2048
// 1-wave blocks; only 2 waves/SIMD but fill-bound doesn't need TLP; VGPR up
// to ~150 is free since only 2 waves exist); (2) DENSE permutation: k-halves
// in separate 1KB regions so every load is base+lane*16 (16 lines/instr, 4
// lanes/line) vs stride-32 (32 lines/instr) — halves TA occupancy, free.
// Screen math unchanged (absmax=0 lineage R15-R20): bf16 hi/lo hh+hl+lh,
// MARGIN=0.06 >= 2x err bound, kappa k-map on BOTH A/B frags;
// C/D row=(l>>4)*4+rg, col=l&15 (m89/m91-verified).
#define D_     64
#define K_     1024
#define N_     65536
#define TPB    64             // 1 wave per block
#define RPB    32             // 2 rowtiles x 16 rows
#define NBLK   (N_ / RPB)     // 2048 blocks
#define MARGIN 0.06f          // screen err bound ~1.4e-2; need >= 2x

typedef __bf16 bf16x8 __attribute__((ext_vector_type(8)));
typedef float  f32x4  __attribute__((ext_vector_type(4)));

__device__ __forceinline__ unsigned short bf16_rne(float f) {
    union { float f; uint32_t u; } v; v.f = f;
    const uint32_t u = v.u;
    return (unsigned short)((u + 0x7fffu + ((u >> 16) & 1u)) >> 16);
}
__device__ __forceinline__ float bf16_tof(unsigned short h) {
    union { uint32_t u; float f; } v; v.u = ((uint32_t)h) << 16;
    return v.f;
}

// ---------------------------------------------------------------------------
// Kernel A: exact fp64 norms (+fp32 copy) and DENSE-PERMUTED bf16 hi/lo
// codebook. Group ct (16 codes) = 4KB block at ct*4096:
//   [0,1K)  hi s=0 : code cl chunk lg at (lg*16+cl)*16
//   [1K,2K) hi s=1 ; [2K,3K) lo s=0 ; [3K,4K) lo s=1
// Main-loop load address = block + lane*16 (+1K/+2K/+3K) -> fully dense.
// 4 threads/code (q4 = lg). 64 blocks x 64 threads.
// ---------------------------------------------------------------------------
__global__ __launch_bounds__(64) void vq_prep(const float* __restrict__ embed,
                                              double* __restrict__ n64,
                                              float* __restrict__ n32,
                                              char* __restrict__ eb) {
    const int gid = blockIdx.x * 64 + threadIdx.x;    // 4096 threads
    const int k   = gid >> 2;
    const int q4  = gid & 3;                          // k-chunk lg of this code
    const float4* e4 = (const float4*)(embed + (size_t)k * D_ + q4 * 16);
    double accA = 0.0, accB = 0.0;                    // 2 indep fp64 chains
    uint32_t hw[8], lw[8];
#pragma unroll
    for (int q = 0; q < 4; ++q) {
        const float4 e = e4[q];
        float c[4] = {e.x, e.y, e.z, e.w};
        unsigned short hb[4], lb[4];
#pragma unroll
        for (int j = 0; j < 4; ++j) {
            hb[j] = bf16_rne(c[j]);
            lb[j] = bf16_rne(c[j] - bf16_tof(hb[j]));
        }
        accA = fma((double)c[0], (double)c[0], accA);
        accB = fma((double)c[1], (double)c[1], accB);
        accA = fma((double)c[2], (double)c[2], accA);
        accB = fma((double)c[3], (double)c[3], accB);
        hw[q * 2]     = (uint32_t)hb[0] | ((uint32_t)hb[1] << 16);
        hw[q * 2 + 1] = (uint32_t)hb[2] | ((uint32_t)hb[3] << 16);
        lw[q * 2]     = (uint32_t)lb[0] | ((uint32_t)lb[1] << 16);
        lw[q * 2 + 1] = (uint32_t)lb[2] | ((uint32_t)lb[3] << 16);
    }
    double acc = accA + accB;
    // butterfly over the quad -> all 4 lanes hold the full norm
    acc += __shfl_xor(acc, 1);
    acc += __shfl_xor(acc, 2);
    if (q4 == 0) { n64[k] = acc; n32[k] = (float)acc; }
    const int ct = k >> 4, cl = k & 15;
    char* base = eb + (size_t)ct * 4096 + (q4 * 16 + cl) * 16;
    int4 h0; h0.x = hw[0]; h0.y = hw[1]; h0.z = hw[2]; h0.w = hw[3];
    int4 h1; h1.x = hw[4]; h1.y = hw[5]; h1.z = hw[6]; h1.w = hw[7];
    int4 l0; l0.x = lw[0]; l0.y = lw[1]; l0.z = lw[2]; l0.w = lw[3];
    int4 l1; l1.x = lw[4]; l1.y = lw[5]; l1.z = lw[6]; l1.w = lw[7];
    *(int4*)(base)        = h0;    // hi s=0
    *(int4*)(base + 1024) = h1;    // hi s=1
    *(int4*)(base + 2048) = l0;    // lo s=0
    *(int4*)(base + 3072) = l1;    // lo s=1
}

// ---------------------------------------------------------------------------
// Kernel B: 1-wave blocks, 2 rowtiles; barrier-free MFMA screen with dense
// L2-stream, fused top-2 + exact fp64 rescan + epilogue.
// Lane (lg=l>>4, lc=l&15): A-rows {t*16+lc}, code-in-group lc, k-chunk lg.
// ---------------------------------------------------------------------------
__global__ __launch_bounds__(TPB) void vq_main(const float* __restrict__ z_e,
                                               const float* __restrict__ embed,
                                               const char* __restrict__ eb,
                                               const float* __restrict__ n32g,
                                               const double* __restrict__ n64g,
                                               float* __restrict__ out,
                                               float* __restrict__ partials) {
    const int lane = threadIdx.x;       // 0..63
    const int lg   = lane >> 4;         // k-chunk / row-group 0..3
    const int lc   = lane & 15;         // A-row in tile / code in group
    const int wrow0 = blockIdx.x * RPB;

    // ---- A-fragments (bf16 hi/lo) for 2 rowtiles ----
    bf16x8 ah[2][2], al[2][2];
#pragma unroll
    for (int t = 0; t < 2; ++t) {
        const float4* xg = (const float4*)(z_e + (size_t)(wrow0 + t * 16 + lc) * D_ + lg * 16);
        float xs[16];
#pragma unroll
        for (int q = 0; q < 4; ++q) {
            const float4 x = xg[q];
            xs[q * 4 + 0] = x.x; xs[q * 4 + 1] = x.y;
            xs[q * 4 + 2] = x.z; xs[q * 4 + 3] = x.w;
        }
#pragma unroll
        for (int s = 0; s < 2; ++s) {
#pragma unroll
            for (int i = 0; i < 8; ++i) {
                const float xf = xs[s * 8 + i];
                const unsigned short hb = bf16_rne(xf);
                const unsigned short lb = bf16_rne(xf - bf16_tof(hb));
                union { unsigned short u; __bf16 h; } uh, ul;
                uh.u = hb; ul.u = lb;
                ah[t][s][i] = uh.h;
                al[t][s][i] = ul.h;
            }
        }
    }

    float b1[2][4], b2[2][4];
    int   i1[2][4];
#pragma unroll
    for (int t = 0; t < 2; ++t)
#pragma unroll
        for (int rg = 0; rg < 4; ++rg) { b1[t][rg] = 3.4e38f; b2[t][rg] = 3.4e38f; i1[t][rg] = 0; }

    // ---- barrier-free K loop: 64 groups of 16 codes, 2-deep dbuf ----
    const char* ebl = eb + lane * 16;   // dense: each load = base + lane*16

#define LOADG(G, R) {                                                     \
        const char* p_ = ebl + (size_t)(G) * 4096;                        \
        R##h0 = *(const int4*)(p_);                                       \
        R##h1 = *(const int4*)(p_ + 1024);                                \
        R##l0 = *(const int4*)(p_ + 2048);                                \
        R##l1 = *(const int4*)(p_ + 3072);                                \
        R##nv = n32g[(G) * 16 + lc];                                      \
    }
#define COMPG(KI, R) {                                                    \
        const bf16x8 bh0 = __builtin_bit_cast(bf16x8, R##h0);             \
        const bf16x8 bh1 = __builtin_bit_cast(bf16x8, R##h1);             \
        const bf16x8 bl0 = __builtin_bit_cast(bf16x8, R##l0);             \
        const bf16x8 bl1 = __builtin_bit_cast(bf16x8, R##l1);             \
        f32x4 a00 = {0.f, 0.f, 0.f, 0.f};                                 \
        f32x4 a01 = {0.f, 0.f, 0.f, 0.f};                                 \
        f32x4 a10 = {0.f, 0.f, 0.f, 0.f};                                 \
        f32x4 a11 = {0.f, 0.f, 0.f, 0.f};                                 \
        a00 = __builtin_amdgcn_mfma_f32_16x16x32_bf16(ah[0][0], bh0, a00, 0, 0, 0); \
        a01 = __builtin_amdgcn_mfma_f32_16x16x32_bf16(ah[0][1], bh1, a01, 0, 0, 0); \
        a10 = __builtin_amdgcn_mfma_f32_16x16x32_bf16(ah[1][0], bh0, a10, 0, 0, 0); \
        a11 = __builtin_amdgcn_mfma_f32_16x16x32_bf16(ah[1][1], bh1, a11, 0, 0, 0); \
        a00 = __builtin_amdgcn_mfma_f32_16x16x32_bf16(al[0][0], bh0, a00, 0, 0, 0); \
        a01 = __builtin_amdgcn_mfma_f32_16x16x32_bf16(al[0][1], bh1, a01, 0, 0, 0); \
        a10 = __builtin_amdgcn_mfma_f32_16x16x32_bf16(al[1][0], bh0, a10, 0, 0, 0); \
        a11 = __builtin_amdgcn_mfma_f32_16x16x32_bf16(al[1][1], bh1, a11, 0, 0, 0); \
        a00 = __builtin_amdgcn_mfma_f32_16x16x32_bf16(ah[0][0], bl0, a00, 0, 0, 0); \
        a01 = __builtin_amdgcn_mfma_f32_16x16x32_bf16(ah[0][1], bl1, a01, 0, 0, 0); \
        a10 = __builtin_amdgcn_mfma_f32_16x16x32_bf16(ah[1][0], bl0, a10, 0, 0, 0); \
        a11 = __builtin_amdgcn_mfma_f32_16x16x32_bf16(ah[1][1], bl1, a11, 0, 0, 0); \
        const int ki_ = (KI) + lc;                                        \
        _Pragma("unroll")                                                 \
        for (int rg = 0; rg < 4; ++rg) {                                  \
            const float s0 = fmaf(-2.0f, a00[rg] + a01[rg], R##nv);       \
            const float s1 = fmaf(-2.0f, a10[rg] + a11[rg], R##nv);       \
            const bool  lt0 = s0 < b1[0][rg];                             \
            const float m20 = fminf(s0, b2[0][rg]);                       \
            b2[0][rg] = lt0 ? b1[0][rg] : m20;                            \
            b1[0][rg] = lt0 ? s0        : b1[0][rg];                      \
            i1[0][rg] = lt0 ? ki_       : i1[0][rg];                      \
            const bool  lt1 = s1 < b1[1][rg];                             \
            const float m21 = fminf(s1, b2[1][rg]);                       \
            b2[1][rg] = lt1 ? b1[1][rg] : m21;                            \
            b1[1][rg] = lt1 ? s1        : b1[1][rg];                      \
            i1[1][rg] = lt1 ? ki_       : i1[1][rg];                      \
        }                                                                 \
    }

    {
        int4 Ah0, Ah1, Al0, Al1; float Anv;
        int4 Bh0, Bh1, Bl0, Bl1; float Bnv;
        LOADG(0, A);
        for (int g = 0; g < 64; g += 2) {
            LOADG(g + 1, B);
            COMPG(g * 16, A);
            const int ng = (g + 2 < 64) ? (g + 2) : 0;   // clamped prefetch
            LOADG(ng, A);
            COMPG((g + 1) * 16, B);
        }
    }
#undef LOADG
#undef COMPG

    // Merge top-2 across the 16 lanes sharing rows (lex (score,idx)).
#pragma unroll
    for (int t = 0; t < 2; ++t)
#pragma unroll
        for (int rg = 0; rg < 4; ++rg)
#pragma unroll
            for (int off = 1; off <= 8; off <<= 1) {
                const float ob1 = __shfl_xor(b1[t][rg], off);
                const float ob2 = __shfl_xor(b2[t][rg], off);
                const int   oi1 = __shfl_xor(i1[t][rg], off);
                if (ob1 < b1[t][rg] || (ob1 == b1[t][rg] && oi1 < i1[t][rg])) {
                    b2[t][rg] = fminf(b1[t][rg], ob2); b1[t][rg] = ob1; i1[t][rg] = oi1;
                } else {
                    b2[t][rg] = fminf(ob1, b2[t][rg]);
                }
            }

    // Near-tie rows: wave-cooperative EXACT fp64 full-K rescan (rare).
#pragma unroll
    for (int t = 0; t < 2; ++t) {
#pragma unroll
        for (int rg = 0; rg < 4; ++rg) {
            for (int g = 0; g < 4; ++g) {          // runtime loop, wave-uniform
                const float g1 = __shfl(b1[t][rg], g << 4);
                const float g2 = __shfl(b2[t][rg], g << 4);
                if (g2 - g1 < MARGIN) {
                    const int grow = wrow0 + t * 16 + g * 4 + rg;
                    const float* xp = z_e + (size_t)grow * D_;
                    double bs = 1.0e300; int bi = 1 << 30;
                    for (int c0 = 0; c0 < K_; c0 += 64) {
                        const int c = c0 + lane;
                        const float* ep = embed + (size_t)c * D_;
                        double dot = 0.0;
#pragma unroll
                        for (int j = 0; j < D_; ++j)
                            dot = fma((double)xp[j], (double)ep[j], dot);
                        const double sc = fma(-2.0, dot, n64g[c]);
                        if (sc < bs) { bs = sc; bi = c; }
                    }
#pragma unroll
                    for (int off = 32; off > 0; off >>= 1) {   // (s,idx) lex-min
                        const double so = __shfl_xor(bs, off);
                        const int    io = __shfl_xor(bi, off);
                        if (so < bs || (so == bs && io < bi)) { bs = so; bi = io; }
                    }
                    if (lg == g) i1[t][rg] = bi;
                }
            }
        }
    }

    // Epilogue: lane owns rows {t*16+lc}, k-chunk lg*16..+16; x rematerialized.
    float sq = 0.f;
#pragma unroll
    for (int t = 0; t < 2; ++t) {
        const int srcl = (lc >> 2) << 4;   // a lane of the group owning row lc
        const int c0v = __shfl(i1[t][0], srcl);
        const int c1v = __shfl(i1[t][1], srcl);
        const int c2v = __shfl(i1[t][2], srcl);
        const int c3v = __shfl(i1[t][3], srcl);
        const int rsel = lc & 3;
        int bidx = (rsel == 0) ? c0v : (rsel == 1) ? c1v : (rsel == 2) ? c2v : c3v;
        bidx &= (K_ - 1);
        const int row = wrow0 + t * 16 + lc;
        const float4* eg = (const float4*)(embed + (size_t)bidx * D_ + lg * 16);
        const float4* xg = (const float4*)(z_e + (size_t)row * D_ + lg * 16);
        float4*       og = (float4*)(out + (size_t)row * D_ + lg * 16);
#pragma unroll
        for (int q = 0; q < 4; ++q) {
            const float4 e = eg[q];
            const float4 x = xg[q];
            const float d0 = e.x - x.x;
            const float d1 = e.y - x.y;
            const float d2 = e.z - x.z;
            const float d3 = e.w - x.w;
            sq = fmaf(d0, d0, sq); sq = fmaf(d1, d1, sq);
            sq = fmaf(d2, d2, sq); sq = fmaf(d3, d3, sq);
            float4 o;                      // x + (e - x): match reference fp32 rounding
            o.x = x.x + d0;
            o.y = x.y + d1;
            o.z = x.z + d2;
            o.w = x.w + d3;
            og[q] = o;
        }
        if (lg == 0) out[(size_t)N_ * D_ + row] = (float)bidx;
    }

    // Wave-level loss reduction (no LDS, no barriers)
#pragma unroll
    for (int off = 32; off > 0; off >>= 1) sq += __shfl_xor(sq, off);
    if (lane == 0) partials[blockIdx.x] = sq;
}

// ---------------------------------------------------------------------------
// Kernel C: reduce NBLK partials -> vq_loss = 1.25 * mean(sqdiff), fp32
// ---------------------------------------------------------------------------
__global__ __launch_bounds__(256) void vq_loss_final(const float* __restrict__ partials,
                                                     float* __restrict__ out) {
    __shared__ float red[256];
    const int tid = threadIdx.x;
    float s = 0.f;
#pragma unroll
    for (int i = 0; i < NBLK / 256; ++i) s += partials[tid + i * 256];
    red[tid] = s;
    __syncthreads();
#pragma unroll
    for (int w = 128; w > 0; w >>= 1) {
        if (tid < w) red[tid] += red[tid + w];
        __syncthreads();
    }
    if (tid == 0)
        out[(size_t)N_ * D_ + N_] = 1.25f * red[0] / (float)((size_t)N_ * D_);
}

// ---------------------------------------------------------------------------
extern "C" void kernel_launch(void* const* d_in, const int* in_sizes, int n_in,
                              void* d_out, int out_size, void* d_ws, size_t ws_size,
                              hipStream_t stream) {
    const float* z_e;
    const float* embed;
    if (in_sizes[0] == N_ * D_) {
        z_e   = (const float*)d_in[0];
        embed = (const float*)d_in[1];
    } else {
        z_e   = (const float*)d_in[1];
        embed = (const float*)d_in[0];
    }
    float* out = (float*)d_out;

    double* n64      = (double*)d_ws;                 // 8 KB
    float*  n32      = (float*)(n64 + K_);            // 4 KB
    float*  partials = n32 + K_;                      // 8 KB
    char*   eb       = (char*)(partials + NBLK);      // 256 KB dense codebook

    vq_prep<<<K_ / 16, 64, 0, stream>>>(embed, n64, n32, eb);
    vq_main<<<NBLK, TPB, 0, stream>>>(z_e, embed, eb, n32, n64, out, partials);
    vq_loss_final<<<1, 256, 0, stream>>>(partials, out);
}